// Round 8
// baseline (594.470 us; speedup 1.0000x reference)
//
#include <hip/hip_runtime.h>
#include <math.h>

#define F 128
#define NLAYERS 2

typedef __attribute__((ext_vector_type(8))) short bf16x8s;
typedef __attribute__((ext_vector_type(8))) unsigned short u16x8;
typedef __attribute__((ext_vector_type(4))) float f32x4;

__device__ __forceinline__ float sigmoidf_(float x) { return 1.0f / (1.0f + expf(-x)); }

__device__ __forceinline__ unsigned short f2bf(float f) {
    unsigned int u = __float_as_uint(f);
    u += 0x7fffu + ((u >> 16) & 1u);  // RNE
    return (unsigned short)(u >> 16);
}
__device__ __forceinline__ float bf2f(unsigned short s) {
    return __uint_as_float(((unsigned int)s) << 16);
}

// ---------------------------------------------------------------------------
// Weight pack: f32 [L][3][256][128] -> bf16 k-octet layout.
//  W1b [L][64][256][8]: gates (r|u) as 256 cols, K=512 parts (x,h,agg_x,agg_h)
//  W2b [L][64][128][8]: gate c, K parts (x, rh, agg_x, agg_rh)
// ---------------------------------------------------------------------------
__global__ void pack_w_bf16(const float* __restrict__ Ws, const float* __restrict__ Wn,
                            unsigned short* __restrict__ W1b, unsigned short* __restrict__ W2b) {
    int t = blockIdx.x * blockDim.x + threadIdx.x;
    const int n1 = 2 * 64 * 256 * 8;  // 262144
    if (t < n1) {
        int j = t & 7, n = (t >> 3) & 255, ko = (t >> 11) & 63, l = t >> 17;
        int k = ko * 8 + j;
        int p = k >> 7, r = k & 127, g = n >> 7, c = n & 127;
        const float* W = (p < 2) ? Ws : Wn;
        W1b[t] = f2bf(W[(((l * 3 + g) * 256) + ((p & 1) * 128 + r)) * 128 + c]);
    } else {
        int t2 = t - n1;
        if (t2 >= 2 * 64 * 128 * 8) return;
        int j = t2 & 7, n = (t2 >> 3) & 127, ko = (t2 >> 10) & 63, l = t2 >> 16;
        int k = ko * 8 + j;
        int p = k >> 7, r = k & 127;
        const float* W = (p < 2) ? Ws : Wn;
        W2b[t2] = f2bf(W[(((l * 3 + 2) * 256) + ((p & 1) * 128 + r)) * 128 + n]);
    }
}

// Fused f32 -> bf16 interleave: x -> xh0[:,0:128], h0 -> xh0[:,128:256],
// h1 -> xh1[:,128:256]. Each t handles 4 floats.
__global__ void cvt_all(const float* __restrict__ x, const float* __restrict__ hidden,
                        unsigned short* __restrict__ xh0, unsigned short* __restrict__ xh1,
                        int n4, size_t NF) {
    int t = blockIdx.x * blockDim.x + threadIdx.x;
    const float* in;
    unsigned short* out;
    int tt;
    if (t < n4) { in = x; out = xh0; tt = t; }
    else if (t < 2 * n4) { in = hidden; out = xh0 + 128; tt = t - n4; }
    else if (t < 3 * n4) { in = hidden + NF; out = xh1 + 128; tt = t - 2 * n4; }
    else return;
    float4 v = reinterpret_cast<const float4*>(in)[tt];
    ushort4 o;
    o.x = f2bf(v.x); o.y = f2bf(v.y); o.z = f2bf(v.z); o.w = f2bf(v.w);
    *reinterpret_cast<ushort4*>(out + (((size_t)(tt >> 5)) << 8) + ((tt & 31) << 2)) = o;
}

// ---------------------------------------------------------------------------
// CSR build with composite key = dst*16 + (src>>12). hist/scatter unrolled x4
// (int4/float4 coalesced loads, 4 independent atomics in flight per thread).
// ---------------------------------------------------------------------------
__global__ void hist_key(const int* __restrict__ src, const int* __restrict__ dst,
                         int* __restrict__ cnt, int E) {
    int t = blockIdx.x * blockDim.x + threadIdx.x;
    int e = t << 2;
    if (e + 3 < E) {
        int4 s = *reinterpret_cast<const int4*>(src + e);
        int4 d = *reinterpret_cast<const int4*>(dst + e);
        atomicAdd(&cnt[(d.x << 4) + (s.x >> 12)], 1);
        atomicAdd(&cnt[(d.y << 4) + (s.y >> 12)], 1);
        atomicAdd(&cnt[(d.z << 4) + (s.z >> 12)], 1);
        atomicAdd(&cnt[(d.w << 4) + (s.w >> 12)], 1);
    } else {
        for (; e < E; ++e) atomicAdd(&cnt[(dst[e] << 4) + (src[e] >> 12)], 1);
    }
}

__global__ __launch_bounds__(1024) void scan_blk(const int* __restrict__ cnt,
                                                 int* __restrict__ offs,
                                                 int* __restrict__ bsum, int n) {
    __shared__ int wsum[16];
    int tid = threadIdx.x, lane = tid & 63, wid = tid >> 6;
    int i = blockIdx.x * 1024 + tid;
    int v = (i < n) ? cnt[i] : 0;
    int incl = v;
#pragma unroll
    for (int off = 1; off < 64; off <<= 1) {
        int t = __shfl_up(incl, off, 64);
        if (lane >= off) incl += t;
    }
    if (lane == 63) wsum[wid] = incl;
    __syncthreads();
    if (wid == 0) {
        int s = (lane < 16) ? wsum[lane] : 0;
#pragma unroll
        for (int off = 1; off < 16; off <<= 1) {
            int t = __shfl_up(s, off, 64);
            if (lane >= off) s += t;
        }
        if (lane < 16) wsum[lane] = s;
    }
    __syncthreads();
    int wbase = (wid > 0) ? wsum[wid - 1] : 0;
    if (i < n) offs[i] = wbase + incl - v;
    if (tid == 1023) bsum[blockIdx.x] = wbase + incl;
}

__global__ __launch_bounds__(1024) void scan_tops(int* __restrict__ bsum, int nb,
                                                  int* __restrict__ total_out) {
    __shared__ int wsum[16];
    int tid = threadIdx.x, lane = tid & 63, wid = tid >> 6;
    int v = (tid < nb) ? bsum[tid] : 0;
    int incl = v;
#pragma unroll
    for (int off = 1; off < 64; off <<= 1) {
        int t = __shfl_up(incl, off, 64);
        if (lane >= off) incl += t;
    }
    if (lane == 63) wsum[wid] = incl;
    __syncthreads();
    if (wid == 0) {
        int s = (lane < 16) ? wsum[lane] : 0;
#pragma unroll
        for (int off = 1; off < 16; off <<= 1) {
            int t = __shfl_up(s, off, 64);
            if (lane >= off) s += t;
        }
        if (lane < 16) wsum[lane] = s;
    }
    __syncthreads();
    int wbase = (wid > 0) ? wsum[wid - 1] : 0;
    if (tid < nb) bsum[tid] = wbase + incl - v;
    if (tid == 1023) *total_out = wbase + incl;
}

__global__ __launch_bounds__(1024) void scan_add(const int* __restrict__ bsum,
                                                 int* __restrict__ offs,
                                                 int* __restrict__ cursor, int n) {
    int i = blockIdx.x * 1024 + threadIdx.x;
    if (i >= n) return;
    int o = offs[i] + bsum[blockIdx.x];
    offs[i] = o;
    cursor[i] = o;
}

__global__ void scatter_edges(const int* __restrict__ src, const int* __restrict__ dst,
                              const float* __restrict__ ew, int* __restrict__ cursor,
                              int2* __restrict__ es, int E) {
    int t = blockIdx.x * blockDim.x + threadIdx.x;
    int e = t << 2;
    if (e + 3 < E) {
        int4 s = *reinterpret_cast<const int4*>(src + e);
        int4 d = *reinterpret_cast<const int4*>(dst + e);
        float4 w = *reinterpret_cast<const float4*>(ew + e);
        int p0 = atomicAdd(&cursor[(d.x << 4) + (s.x >> 12)], 1);
        int p1 = atomicAdd(&cursor[(d.y << 4) + (s.y >> 12)], 1);
        int p2 = atomicAdd(&cursor[(d.z << 4) + (s.z >> 12)], 1);
        int p3 = atomicAdd(&cursor[(d.w << 4) + (s.w >> 12)], 1);
        es[p0] = make_int2(s.x, __float_as_int(w.x));
        es[p1] = make_int2(s.y, __float_as_int(w.y));
        es[p2] = make_int2(s.z, __float_as_int(w.z));
        es[p3] = make_int2(s.w, __float_as_int(w.w));
    } else {
        for (; e < E; ++e) {
            int s = src[e];
            int p = atomicAdd(&cursor[(dst[e] << 4) + (s >> 12)], 1);
            es[p] = make_int2(s, __float_as_int(ew[e]));
        }
    }
}

// ---------------------------------------------------------------------------
// CSR aggregation over interleaved xh[N][256] bf16: 32 lanes/node, each lane
// one 16B (ushort8) gather per edge. Node segment = offs2[n*16 .. n*16+16).
// ---------------------------------------------------------------------------
__global__ __launch_bounds__(256) void agg_csr2_i(
    const unsigned short* __restrict__ XH,
    const int2* __restrict__ es, const int* __restrict__ offs2,
    unsigned short* __restrict__ agg0, unsigned short* __restrict__ agg1, int N) {
    int node = blockIdx.x * 8 + (threadIdx.x >> 5);
    if (node >= N) return;
    int lane = threadIdx.x & 31;
    int beg = offs2[node << 4], end = offs2[(node << 4) + 16];
    float a0[8] = {0, 0, 0, 0, 0, 0, 0, 0};
    float a1[8] = {0, 0, 0, 0, 0, 0, 0, 0};
    int loff = lane << 3;
    int i = beg;
    for (; i + 3 < end; i += 4) {
        int2 e0 = es[i], e1 = es[i + 1], e2 = es[i + 2], e3 = es[i + 3];
        u16x8 v0 = *reinterpret_cast<const u16x8*>(XH + (((size_t)e0.x) << 8) + loff);
        u16x8 v1 = *reinterpret_cast<const u16x8*>(XH + (((size_t)e1.x) << 8) + loff);
        u16x8 v2 = *reinterpret_cast<const u16x8*>(XH + (((size_t)e2.x) << 8) + loff);
        u16x8 v3 = *reinterpret_cast<const u16x8*>(XH + (((size_t)e3.x) << 8) + loff);
        float w0 = __int_as_float(e0.y), w1 = __int_as_float(e1.y);
        float w2 = __int_as_float(e2.y), w3 = __int_as_float(e3.y);
#pragma unroll
        for (int j = 0; j < 8; ++j) {
            a0[j] += w0 * bf2f(v0[j]);
            a1[j] += w1 * bf2f(v1[j]);
            a0[j] += w2 * bf2f(v2[j]);
            a1[j] += w3 * bf2f(v3[j]);
        }
    }
    for (; i < end; ++i) {
        int2 e0 = es[i];
        float w0 = __int_as_float(e0.y);
        u16x8 v0 = *reinterpret_cast<const u16x8*>(XH + (((size_t)e0.x) << 8) + loff);
#pragma unroll
        for (int j = 0; j < 8; ++j) a0[j] += w0 * bf2f(v0[j]);
    }
    u16x8 o;
#pragma unroll
    for (int j = 0; j < 8; ++j) o[j] = f2bf(a0[j] + a1[j]);
    unsigned short* op = (lane < 16)
        ? (agg0 + (((size_t)node) << 7) + (lane << 3))
        : (agg1 + (((size_t)node) << 7) + ((lane & 15) << 3));
    *reinterpret_cast<u16x8*>(op) = o;
}

// Single-table CSR aggregation (rh, [N][128] bf16): 32 lanes x 8B, unroll-4.
__global__ __launch_bounds__(256) void agg_csr1_b(
    const unsigned short* __restrict__ V0,
    const int2* __restrict__ es, const int* __restrict__ offs2,
    unsigned short* __restrict__ agg0, int N) {
    int node = blockIdx.x * 8 + (threadIdx.x >> 5);
    if (node >= N) return;
    int lane = threadIdx.x & 31;
    int beg = offs2[node << 4], end = offs2[(node << 4) + 16];
    float p0[4] = {0, 0, 0, 0}, p1[4] = {0, 0, 0, 0};
    int loff = lane << 2;
    int i = beg;
    for (; i + 3 < end; i += 4) {
        int2 e0 = es[i], e1 = es[i + 1], e2 = es[i + 2], e3 = es[i + 3];
        ushort4 x0 = *reinterpret_cast<const ushort4*>(V0 + (((size_t)e0.x) << 7) + loff);
        ushort4 x1 = *reinterpret_cast<const ushort4*>(V0 + (((size_t)e1.x) << 7) + loff);
        ushort4 x2 = *reinterpret_cast<const ushort4*>(V0 + (((size_t)e2.x) << 7) + loff);
        ushort4 x3 = *reinterpret_cast<const ushort4*>(V0 + (((size_t)e3.x) << 7) + loff);
        float w0 = __int_as_float(e0.y), w1 = __int_as_float(e1.y);
        float w2 = __int_as_float(e2.y), w3 = __int_as_float(e3.y);
        p0[0] += w0 * bf2f(x0.x); p0[1] += w0 * bf2f(x0.y);
        p0[2] += w0 * bf2f(x0.z); p0[3] += w0 * bf2f(x0.w);
        p1[0] += w1 * bf2f(x1.x); p1[1] += w1 * bf2f(x1.y);
        p1[2] += w1 * bf2f(x1.z); p1[3] += w1 * bf2f(x1.w);
        p0[0] += w2 * bf2f(x2.x); p0[1] += w2 * bf2f(x2.y);
        p0[2] += w2 * bf2f(x2.z); p0[3] += w2 * bf2f(x2.w);
        p1[0] += w3 * bf2f(x3.x); p1[1] += w3 * bf2f(x3.y);
        p1[2] += w3 * bf2f(x3.z); p1[3] += w3 * bf2f(x3.w);
    }
    for (; i < end; ++i) {
        int2 e0 = es[i];
        float w0 = __int_as_float(e0.y);
        ushort4 x0 = *reinterpret_cast<const ushort4*>(V0 + (((size_t)e0.x) << 7) + loff);
        p0[0] += w0 * bf2f(x0.x); p0[1] += w0 * bf2f(x0.y);
        p0[2] += w0 * bf2f(x0.z); p0[3] += w0 * bf2f(x0.w);
    }
    size_t ob = (((size_t)node) << 7) + loff;
    ushort4 o0;
    o0.x = f2bf(p0[0] + p1[0]); o0.y = f2bf(p0[1] + p1[1]);
    o0.z = f2bf(p0[2] + p1[2]); o0.w = f2bf(p0[3] + p1[3]);
    *reinterpret_cast<ushort4*>(agg0 + ob) = o0;
}

// ---------------------------------------------------------------------------
// GEMM gates r|u: 128x128 tile, y-grid=2 over 256 cols, K=512, 512 threads,
// 8 waves (2x4), wave tile 64x32 (acc 4x2), double-buffered LDS (32KB).
// A parts: x,h from xh (stride 256), aggx/aggh (stride 128). B = W1b k-octet.
// Epilogue: col<128 -> rhb = bf16(sigmoid*h); col>=128 -> u = sigmoid (f32)
// ---------------------------------------------------------------------------
__global__ __launch_bounds__(512) void gemm_ru(
    const unsigned short* __restrict__ XH,
    const unsigned short* __restrict__ AGGX, const unsigned short* __restrict__ AGGH,
    const unsigned short* __restrict__ Wb, const float* __restrict__ bias,
    const float* __restrict__ hfull,
    unsigned short* __restrict__ rhb, float* __restrict__ u, int N) {
    __shared__ __align__(16) unsigned short Als[2][4 * 128 * 8];  // 8KB x2
    __shared__ __align__(16) unsigned short Bls[2][4 * 128 * 8];  // 8KB x2

    int tid = threadIdx.x;
    int row0 = blockIdx.x * 128;
    int n0c = blockIdx.y * 128;
    int lane = tid & 63;
    int w = tid >> 6;               // 8 waves
    int wrow = (w & 1) << 6;        // 0 / 64
    int wcol = (w >> 1) << 5;       // 0 / 32 / 64 / 96
    int quad = lane >> 4, l16 = lane & 15;

    f32x4 acc[4][2];
    const f32x4 z4 = {0.f, 0.f, 0.f, 0.f};
#pragma unroll
    for (int mt = 0; mt < 4; ++mt)
#pragma unroll
        for (int nt = 0; nt < 2; ++nt) acc[mt][nt] = z4;

    int mA = tid & 127, qA = tid >> 7;  // staging: one (q,m) pair per thread
    int growA = row0 + mA;
    if (growA >= N) growA = N - 1;
    int nB = tid & 127, qB = tid >> 7;

    auto stage = [&](int ks, int buf) {
        int p = ks >> 7;
        const unsigned short* ga =
            (p == 0) ? (XH + (size_t)growA * 256 + (ks & 127) + (qA << 3))
          : (p == 1) ? (XH + (size_t)growA * 256 + 128 + (ks & 127) + (qA << 3))
          : (p == 2) ? (AGGX + ((size_t)growA << 7) + (ks & 127) + (qA << 3))
                     : (AGGH + ((size_t)growA << 7) + (ks & 127) + (qA << 3));
        __builtin_amdgcn_global_load_lds(
            (const __attribute__((address_space(1))) void*)ga,
            (__attribute__((address_space(3))) void*)&Als[buf][((qA << 7) + mA) << 3], 16, 0, 0);
        int koG = (ks >> 3) + qB;
        const unsigned short* gb = Wb + ((size_t)(koG * 256 + n0c + nB) << 3);
        __builtin_amdgcn_global_load_lds(
            (const __attribute__((address_space(1))) void*)gb,
            (__attribute__((address_space(3))) void*)&Bls[buf][((qB << 7) + nB) << 3], 16, 0, 0);
    };

    stage(0, 0);
    __syncthreads();
    int buf = 0;
    for (int ks = 0; ks < 512; ks += 32, buf ^= 1) {
        if (ks + 32 < 512) stage(ks + 32, buf ^ 1);

        bf16x8s af[4], bfr[2];
#pragma unroll
        for (int mt = 0; mt < 4; ++mt)
            af[mt] = *reinterpret_cast<const bf16x8s*>(
                &Als[buf][((quad << 7) + wrow + (mt << 4) + l16) << 3]);
#pragma unroll
        for (int nt = 0; nt < 2; ++nt)
            bfr[nt] = *reinterpret_cast<const bf16x8s*>(
                &Bls[buf][((quad << 7) + wcol + (nt << 4) + l16) << 3]);
#pragma unroll
        for (int mt = 0; mt < 4; ++mt)
#pragma unroll
            for (int nt = 0; nt < 2; ++nt)
                acc[mt][nt] = __builtin_amdgcn_mfma_f32_16x16x32_bf16(
                    af[mt], bfr[nt], acc[mt][nt], 0, 0, 0);
        __syncthreads();
    }

#pragma unroll
    for (int mt = 0; mt < 4; ++mt) {
#pragma unroll
        for (int reg = 0; reg < 4; ++reg) {
            int row = row0 + wrow + (mt << 4) + (quad << 2) + reg;
            if (row >= N) continue;
#pragma unroll
            for (int nt = 0; nt < 2; ++nt) {
                int col = n0c + wcol + (nt << 4) + l16;
                float val = acc[mt][nt][reg] + bias[col];
                float sg = sigmoidf_(val);
                int c = col & 127;
                size_t o = ((size_t)row << 7) + c;
                if (col < 128)
                    rhb[o] = f2bf(sg * hfull[o]);   // rh = r*h (bf16)
                else
                    u[o] = sg;                       // u (f32)
            }
        }
    }
}

// ---------------------------------------------------------------------------
// GEMM gate c: 128x128 tile, K=512, 512 threads, 8 waves (2x4), acc 4x2.
// A parts: x (xh stride 256), rh (128), aggx (128), agg_rh (128). B = W2b.
// Epilogue: c = sigmoid; hn = u*h+(1-u)*c -> outf (+outf2); outb = bf16(hn)
// with row shift obsh (8 -> next xh cols 0:128, 7 -> plain 128-col table).
// ---------------------------------------------------------------------------
__global__ __launch_bounds__(512) void gemm_c(
    const unsigned short* __restrict__ XH, const unsigned short* __restrict__ RHB,
    const unsigned short* __restrict__ AGGX, const unsigned short* __restrict__ AGGR,
    const unsigned short* __restrict__ Wb, const float* __restrict__ bias,
    const float* __restrict__ hfull, const float* __restrict__ uin,
    unsigned short* __restrict__ outb, float* __restrict__ outf,
    float* __restrict__ outf2, int obsh, int N) {
    __shared__ __align__(16) unsigned short Als[2][4 * 128 * 8];  // 8KB x2
    __shared__ __align__(16) unsigned short Bls[2][4 * 128 * 8];  // 8KB x2

    int tid = threadIdx.x;
    int row0 = blockIdx.x * 128;
    int lane = tid & 63;
    int w = tid >> 6;
    int wrow = (w & 1) << 6;
    int wcol = (w >> 1) << 5;
    int quad = lane >> 4, l16 = lane & 15;

    f32x4 acc[4][2];
    const f32x4 z4 = {0.f, 0.f, 0.f, 0.f};
#pragma unroll
    for (int mt = 0; mt < 4; ++mt)
#pragma unroll
        for (int nt = 0; nt < 2; ++nt) acc[mt][nt] = z4;

    int mA = tid & 127, qA = tid >> 7;
    int growA = row0 + mA;
    if (growA >= N) growA = N - 1;
    int nB = tid & 127, qB = tid >> 7;

    auto stage = [&](int ks, int buf) {
        int p = ks >> 7;
        const unsigned short* ga =
            (p == 0) ? (XH + (size_t)growA * 256 + (ks & 127) + (qA << 3))
          : (p == 1) ? (RHB + ((size_t)growA << 7) + (ks & 127) + (qA << 3))
          : (p == 2) ? (AGGX + ((size_t)growA << 7) + (ks & 127) + (qA << 3))
                     : (AGGR + ((size_t)growA << 7) + (ks & 127) + (qA << 3));
        __builtin_amdgcn_global_load_lds(
            (const __attribute__((address_space(1))) void*)ga,
            (__attribute__((address_space(3))) void*)&Als[buf][((qA << 7) + mA) << 3], 16, 0, 0);
        int koG = (ks >> 3) + qB;
        const unsigned short* gb = Wb + ((size_t)(koG * 128 + nB) << 3);
        __builtin_amdgcn_global_load_lds(
            (const __attribute__((address_space(1))) void*)gb,
            (__attribute__((address_space(3))) void*)&Bls[buf][((qB << 7) + nB) << 3], 16, 0, 0);
    };

    stage(0, 0);
    __syncthreads();
    int buf = 0;
    for (int ks = 0; ks < 512; ks += 32, buf ^= 1) {
        if (ks + 32 < 512) stage(ks + 32, buf ^ 1);

        bf16x8s af[4], bfr[2];
#pragma unroll
        for (int mt = 0; mt < 4; ++mt)
            af[mt] = *reinterpret_cast<const bf16x8s*>(
                &Als[buf][((quad << 7) + wrow + (mt << 4) + l16) << 3]);
#pragma unroll
        for (int nt = 0; nt < 2; ++nt)
            bfr[nt] = *reinterpret_cast<const bf16x8s*>(
                &Bls[buf][((quad << 7) + wcol + (nt << 4) + l16) << 3]);
#pragma unroll
        for (int mt = 0; mt < 4; ++mt)
#pragma unroll
            for (int nt = 0; nt < 2; ++nt)
                acc[mt][nt] = __builtin_amdgcn_mfma_f32_16x16x32_bf16(
                    af[mt], bfr[nt], acc[mt][nt], 0, 0, 0);
        __syncthreads();
    }

#pragma unroll
    for (int mt = 0; mt < 4; ++mt) {
#pragma unroll
        for (int reg = 0; reg < 4; ++reg) {
            int row = row0 + wrow + (mt << 4) + (quad << 2) + reg;
            if (row >= N) continue;
#pragma unroll
            for (int nt = 0; nt < 2; ++nt) {
                int col = wcol + (nt << 4) + l16;
                float val = acc[mt][nt][reg] + bias[col];
                float cv = sigmoidf_(val);
                size_t o = ((size_t)row << 7) + col;
                float uu = uin[o];
                float hh = hfull[o];
                float hn = uu * hh + (1.0f - uu) * cv;
                outf[o] = hn;
                if (outf2) outf2[o] = hn;
                outb[((size_t)row << obsh) + col] = f2bf(hn);  // next layer's x
            }
        }
    }
}

// ---------------------------------------------------------------------------
extern "C" void kernel_launch(void* const* d_in, const int* in_sizes, int n_in,
                              void* d_out, int out_size, void* d_ws, size_t ws_size,
                              hipStream_t stream) {
    const float* x      = (const float*)d_in[0];
    const float* hidden = (const float*)d_in[1];
    const int*   src    = (const int*)d_in[2];
    const int*   dst    = (const int*)d_in[3];
    const float* ew     = (const float*)d_in[4];
    const float* Wself  = (const float*)d_in[5];
    const float* Wneigh = (const float*)d_in[6];
    const float* bias   = (const float*)d_in[7];
    float* out = (float*)d_out;

    int N = in_sizes[0] / F;  // 50000
    int E = in_sizes[2];      // 800000
    size_t NF = (size_t)N * F;
    int NK = N * 16;          // composite key space: dst*16 + src-bucket

    char* p = (char*)d_ws;
    auto alloc = [&](size_t bytes) { char* r = p; p += (bytes + 255) & ~255ull; return r; };
    unsigned short* xh0    = (unsigned short*)alloc(2 * NF * 2);  // [N][256] x|h layer0
    unsigned short* xh1    = (unsigned short*)alloc(2 * NF * 2);  // [N][256] x|h layer1
    unsigned short* agg_xb = (unsigned short*)alloc(NF * 2);
    unsigned short* agg_hb = (unsigned short*)alloc(NF * 2);
    unsigned short* agg_rb = (unsigned short*)alloc(NF * 2);
    unsigned short* rhb    = (unsigned short*)alloc(NF * 2);
    float*          u      = (float*)alloc(NF * 4);
    unsigned short* W1b    = (unsigned short*)alloc(2 * 64 * 256 * 8 * 2);
    unsigned short* W2b    = (unsigned short*)alloc(2 * 64 * 128 * 8 * 2);
    int2*           es     = (int2*)alloc((size_t)E * 8);
    int*            cnt2   = (int*)alloc((size_t)NK * 4);
    int*            offs2  = (int*)alloc(((size_t)NK + 1) * 4);
    int*            cur2   = (int*)alloc((size_t)NK * 4);
    int*            bsum   = (int*)alloc(1024 * 4);

    pack_w_bf16<<<dim3(1536), dim3(256), 0, stream>>>(Wself, Wneigh, W1b, W2b);
    int n4 = (int)(NF / 4);
    cvt_all<<<dim3((3 * n4 + 255) / 256), dim3(256), 0, stream>>>(x, hidden, xh0, xh1, n4, NF);

    hipMemsetAsync(cnt2, 0, (size_t)NK * sizeof(int), stream);
    int e4Blocks = (E / 4 + 255) / 256;
    hist_key<<<dim3(e4Blocks), dim3(256), 0, stream>>>(src, dst, cnt2, E);
    int nb = (NK + 1023) / 1024;  // 782 (<= 1024)
    scan_blk<<<dim3(nb), dim3(1024), 0, stream>>>(cnt2, offs2, bsum, NK);
    scan_tops<<<dim3(1), dim3(1024), 0, stream>>>(bsum, nb, offs2 + NK);
    scan_add<<<dim3(nb), dim3(1024), 0, stream>>>(bsum, offs2, cur2, NK);
    scatter_edges<<<dim3(e4Blocks), dim3(256), 0, stream>>>(src, dst, ew, cur2, es, E);

    float* out_x  = out;
    float* out_h1 = out + NF;
    float* out_h2 = out + 2 * NF;

    int aggBlocks = (N + 7) / 8;
    int mBlocks = (N + 127) / 128;  // 391
    for (int l = 0; l < NLAYERS; ++l) {
        unsigned short* xhL = (l == 0) ? xh0 : xh1;
        const float* hL = hidden + (size_t)l * NF;
        const float* biasL = bias + (size_t)l * 384;

        agg_csr2_i<<<dim3(aggBlocks), dim3(256), 0, stream>>>(xhL, es, offs2,
                                                              agg_xb, agg_hb, N);

        gemm_ru<<<dim3(mBlocks, 2), dim3(512), 0, stream>>>(
            xhL, agg_xb, agg_hb,
            W1b + (size_t)l * 64 * 256 * 8, biasL, hL,
            rhb, u, N);

        agg_csr1_b<<<dim3(aggBlocks), dim3(256), 0, stream>>>(rhb, es, offs2, agg_rb, N);

        float* o1 = (l == 0) ? out_h1 : out_h2;
        float* o2 = (l == NLAYERS - 1) ? out_x : nullptr;
        // l==0: outb -> xh1 cols 0:128 (stride 256, obsh=8) = next layer's x.
        // l==1: outb dead; reuse agg_rb (each block writes only its own rows,
        //       after its last staged read of them) with obsh=7.
        unsigned short* obN = (l == 0) ? xh1 : agg_rb;
        int obsh = (l == 0) ? 8 : 7;
        gemm_c<<<dim3(mBlocks), dim3(512), 0, stream>>>(
            xhL, rhb, agg_xb, agg_rb,
            W2b + (size_t)l * 64 * 128 * 8, biasL + 256, hL, u,
            obN, o1, o2, obsh, N);
    }
}

// Round 9
// 589.954 us; speedup vs baseline: 1.0077x; 1.0077x over previous
//
#include <hip/hip_runtime.h>
#include <math.h>

#define F 128
#define NLAYERS 2

typedef __attribute__((ext_vector_type(8))) short bf16x8s;
typedef __attribute__((ext_vector_type(8))) unsigned short u16x8;
typedef __attribute__((ext_vector_type(4))) float f32x4;

__device__ __forceinline__ float sigmoidf_(float x) { return 1.0f / (1.0f + expf(-x)); }

__device__ __forceinline__ unsigned short f2bf(float f) {
    unsigned int u = __float_as_uint(f);
    u += 0x7fffu + ((u >> 16) & 1u);  // RNE
    return (unsigned short)(u >> 16);
}
__device__ __forceinline__ float bf2f(unsigned short s) {
    return __uint_as_float(((unsigned int)s) << 16);
}

// ---------------------------------------------------------------------------
// Fused prologue: one dispatch covering three independent jobs by block range.
//  [0, CVT)           : f32 -> bf16 interleave (x->xh0[:,0:128], h0->xh0[:,128:],
//                       h1->xh1[:,128:])
//  [CVT, CVT+1536)    : weight pack -> W1b / W2b k-octet layout
//  [CVT+1536, +HIST)  : dst histogram (unroll-2)
// ---------------------------------------------------------------------------
__global__ void prologue(const float* __restrict__ x, const float* __restrict__ hidden,
                         const float* __restrict__ Ws, const float* __restrict__ Wn,
                         const int* __restrict__ dst,
                         unsigned short* __restrict__ xh0, unsigned short* __restrict__ xh1,
                         unsigned short* __restrict__ W1b, unsigned short* __restrict__ W2b,
                         int* __restrict__ cnt, int n4, size_t NF, int E, int cvtBlocks) {
    int b = blockIdx.x;
    int tid = threadIdx.x;
    if (b < cvtBlocks) {
        int t = b * 256 + tid;
        const float* in;
        unsigned short* out;
        int tt;
        if (t < n4) { in = x; out = xh0; tt = t; }
        else if (t < 2 * n4) { in = hidden; out = xh0 + 128; tt = t - n4; }
        else if (t < 3 * n4) { in = hidden + NF; out = xh1 + 128; tt = t - 2 * n4; }
        else return;
        float4 v = reinterpret_cast<const float4*>(in)[tt];
        ushort4 o;
        o.x = f2bf(v.x); o.y = f2bf(v.y); o.z = f2bf(v.z); o.w = f2bf(v.w);
        *reinterpret_cast<ushort4*>(out + (((size_t)(tt >> 5)) << 8) + ((tt & 31) << 2)) = o;
    } else if (b < cvtBlocks + 1536) {
        int t = (b - cvtBlocks) * 256 + tid;
        const int n1 = 2 * 64 * 256 * 8;  // 262144
        if (t < n1) {
            int j = t & 7, n = (t >> 3) & 255, ko = (t >> 11) & 63, l = t >> 17;
            int k = ko * 8 + j;
            int p = k >> 7, r = k & 127, g = n >> 7, c = n & 127;
            const float* W = (p < 2) ? Ws : Wn;
            W1b[t] = f2bf(W[(((l * 3 + g) * 256) + ((p & 1) * 128 + r)) * 128 + c]);
        } else {
            int t2 = t - n1;
            if (t2 >= 2 * 64 * 128 * 8) return;
            int j = t2 & 7, n = (t2 >> 3) & 127, ko = (t2 >> 10) & 63, l = t2 >> 16;
            int k = ko * 8 + j;
            int p = k >> 7, r = k & 127;
            const float* W = (p < 2) ? Ws : Wn;
            W2b[t2] = f2bf(W[(((l * 3 + 2) * 256) + ((p & 1) * 128 + r)) * 128 + n]);
        }
    } else {
        int t = (b - cvtBlocks - 1536) * 256 + tid;
        int e = t << 1;
        if (e + 1 < E) {
            int2 d = *reinterpret_cast<const int2*>(dst + e);
            atomicAdd(&cnt[d.x], 1);
            atomicAdd(&cnt[d.y], 1);
        } else if (e < E) {
            atomicAdd(&cnt[dst[e]], 1);
        }
    }
}

// ---------------------------------------------------------------------------
// Parallel exclusive scan over N node counts (3 kernels).
// ---------------------------------------------------------------------------
__global__ __launch_bounds__(1024) void scan_blk(const int* __restrict__ cnt,
                                                 int* __restrict__ offs,
                                                 int* __restrict__ bsum, int n) {
    __shared__ int wsum[16];
    int tid = threadIdx.x, lane = tid & 63, wid = tid >> 6;
    int i = blockIdx.x * 1024 + tid;
    int v = (i < n) ? cnt[i] : 0;
    int incl = v;
#pragma unroll
    for (int off = 1; off < 64; off <<= 1) {
        int t = __shfl_up(incl, off, 64);
        if (lane >= off) incl += t;
    }
    if (lane == 63) wsum[wid] = incl;
    __syncthreads();
    if (wid == 0) {
        int s = (lane < 16) ? wsum[lane] : 0;
#pragma unroll
        for (int off = 1; off < 16; off <<= 1) {
            int t = __shfl_up(s, off, 64);
            if (lane >= off) s += t;
        }
        if (lane < 16) wsum[lane] = s;
    }
    __syncthreads();
    int wbase = (wid > 0) ? wsum[wid - 1] : 0;
    if (i < n) offs[i] = wbase + incl - v;
    if (tid == 1023) bsum[blockIdx.x] = wbase + incl;
}

__global__ __launch_bounds__(1024) void scan_tops(int* __restrict__ bsum, int nb,
                                                  int* __restrict__ total_out) {
    __shared__ int wsum[16];
    int tid = threadIdx.x, lane = tid & 63, wid = tid >> 6;
    int v = (tid < nb) ? bsum[tid] : 0;
    int incl = v;
#pragma unroll
    for (int off = 1; off < 64; off <<= 1) {
        int t = __shfl_up(incl, off, 64);
        if (lane >= off) incl += t;
    }
    if (lane == 63) wsum[wid] = incl;
    __syncthreads();
    if (wid == 0) {
        int s = (lane < 16) ? wsum[lane] : 0;
#pragma unroll
        for (int off = 1; off < 16; off <<= 1) {
            int t = __shfl_up(s, off, 64);
            if (lane >= off) s += t;
        }
        if (lane < 16) wsum[lane] = s;
    }
    __syncthreads();
    int wbase = (wid > 0) ? wsum[wid - 1] : 0;
    if (tid < nb) bsum[tid] = wbase + incl - v;
    if (tid == 1023) *total_out = wbase + incl;
}

__global__ __launch_bounds__(1024) void scan_add(const int* __restrict__ bsum,
                                                 int* __restrict__ offs,
                                                 int* __restrict__ cursor, int n) {
    int i = blockIdx.x * 1024 + threadIdx.x;
    if (i >= n) return;
    int o = offs[i] + bsum[blockIdx.x];
    offs[i] = o;
    cursor[i] = o;
}

// Scatter edges into CSR order (unroll-2: int2/float2 coalesced loads,
// 2 independent atomic+store chains per thread).
__global__ void scatter_edges(const int* __restrict__ src, const int* __restrict__ dst,
                              const float* __restrict__ ew, int* __restrict__ cursor,
                              int2* __restrict__ es, int E) {
    int t = blockIdx.x * blockDim.x + threadIdx.x;
    int e = t << 1;
    if (e + 1 < E) {
        int2 s = *reinterpret_cast<const int2*>(src + e);
        int2 d = *reinterpret_cast<const int2*>(dst + e);
        float2 w = *reinterpret_cast<const float2*>(ew + e);
        int p0 = atomicAdd(&cursor[d.x], 1);
        int p1 = atomicAdd(&cursor[d.y], 1);
        es[p0] = make_int2(s.x, __float_as_int(w.x));
        es[p1] = make_int2(s.y, __float_as_int(w.y));
    } else if (e < E) {
        int s = src[e];
        int p = atomicAdd(&cursor[dst[e]], 1);
        es[p] = make_int2(s, __float_as_int(ew[e]));
    }
}

// ---------------------------------------------------------------------------
// CSR aggregation over interleaved xh[N][256] bf16: 32 lanes/node, each lane
// one 16B (ushort8) gather per edge. Node segment = offs[n .. n+1).
// ---------------------------------------------------------------------------
__global__ __launch_bounds__(256) void agg_csr2_i(
    const unsigned short* __restrict__ XH,
    const int2* __restrict__ es, const int* __restrict__ offs,
    unsigned short* __restrict__ agg0, unsigned short* __restrict__ agg1, int N) {
    int node = blockIdx.x * 8 + (threadIdx.x >> 5);
    if (node >= N) return;
    int lane = threadIdx.x & 31;
    int beg = offs[node], end = offs[node + 1];
    float a0[8] = {0, 0, 0, 0, 0, 0, 0, 0};
    float a1[8] = {0, 0, 0, 0, 0, 0, 0, 0};
    int loff = lane << 3;
    int i = beg;
    for (; i + 3 < end; i += 4) {
        int2 e0 = es[i], e1 = es[i + 1], e2 = es[i + 2], e3 = es[i + 3];
        u16x8 v0 = *reinterpret_cast<const u16x8*>(XH + (((size_t)e0.x) << 8) + loff);
        u16x8 v1 = *reinterpret_cast<const u16x8*>(XH + (((size_t)e1.x) << 8) + loff);
        u16x8 v2 = *reinterpret_cast<const u16x8*>(XH + (((size_t)e2.x) << 8) + loff);
        u16x8 v3 = *reinterpret_cast<const u16x8*>(XH + (((size_t)e3.x) << 8) + loff);
        float w0 = __int_as_float(e0.y), w1 = __int_as_float(e1.y);
        float w2 = __int_as_float(e2.y), w3 = __int_as_float(e3.y);
#pragma unroll
        for (int j = 0; j < 8; ++j) {
            a0[j] += w0 * bf2f(v0[j]);
            a1[j] += w1 * bf2f(v1[j]);
            a0[j] += w2 * bf2f(v2[j]);
            a1[j] += w3 * bf2f(v3[j]);
        }
    }
    for (; i < end; ++i) {
        int2 e0 = es[i];
        float w0 = __int_as_float(e0.y);
        u16x8 v0 = *reinterpret_cast<const u16x8*>(XH + (((size_t)e0.x) << 8) + loff);
#pragma unroll
        for (int j = 0; j < 8; ++j) a0[j] += w0 * bf2f(v0[j]);
    }
    u16x8 o;
#pragma unroll
    for (int j = 0; j < 8; ++j) o[j] = f2bf(a0[j] + a1[j]);
    unsigned short* op = (lane < 16)
        ? (agg0 + (((size_t)node) << 7) + (lane << 3))
        : (agg1 + (((size_t)node) << 7) + ((lane & 15) << 3));
    *reinterpret_cast<u16x8*>(op) = o;
}

// Single-table CSR aggregation (rh, [N][128] bf16): 32 lanes x 8B, unroll-4.
__global__ __launch_bounds__(256) void agg_csr1_b(
    const unsigned short* __restrict__ V0,
    const int2* __restrict__ es, const int* __restrict__ offs,
    unsigned short* __restrict__ agg0, int N) {
    int node = blockIdx.x * 8 + (threadIdx.x >> 5);
    if (node >= N) return;
    int lane = threadIdx.x & 31;
    int beg = offs[node], end = offs[node + 1];
    float p0[4] = {0, 0, 0, 0}, p1[4] = {0, 0, 0, 0};
    int loff = lane << 2;
    int i = beg;
    for (; i + 3 < end; i += 4) {
        int2 e0 = es[i], e1 = es[i + 1], e2 = es[i + 2], e3 = es[i + 3];
        ushort4 x0 = *reinterpret_cast<const ushort4*>(V0 + (((size_t)e0.x) << 7) + loff);
        ushort4 x1 = *reinterpret_cast<const ushort4*>(V0 + (((size_t)e1.x) << 7) + loff);
        ushort4 x2 = *reinterpret_cast<const ushort4*>(V0 + (((size_t)e2.x) << 7) + loff);
        ushort4 x3 = *reinterpret_cast<const ushort4*>(V0 + (((size_t)e3.x) << 7) + loff);
        float w0 = __int_as_float(e0.y), w1 = __int_as_float(e1.y);
        float w2 = __int_as_float(e2.y), w3 = __int_as_float(e3.y);
        p0[0] += w0 * bf2f(x0.x); p0[1] += w0 * bf2f(x0.y);
        p0[2] += w0 * bf2f(x0.z); p0[3] += w0 * bf2f(x0.w);
        p1[0] += w1 * bf2f(x1.x); p1[1] += w1 * bf2f(x1.y);
        p1[2] += w1 * bf2f(x1.z); p1[3] += w1 * bf2f(x1.w);
        p0[0] += w2 * bf2f(x2.x); p0[1] += w2 * bf2f(x2.y);
        p0[2] += w2 * bf2f(x2.z); p0[3] += w2 * bf2f(x2.w);
        p1[0] += w3 * bf2f(x3.x); p1[1] += w3 * bf2f(x3.y);
        p1[2] += w3 * bf2f(x3.z); p1[3] += w3 * bf2f(x3.w);
    }
    for (; i < end; ++i) {
        int2 e0 = es[i];
        float w0 = __int_as_float(e0.y);
        ushort4 x0 = *reinterpret_cast<const ushort4*>(V0 + (((size_t)e0.x) << 7) + loff);
        p0[0] += w0 * bf2f(x0.x); p0[1] += w0 * bf2f(x0.y);
        p0[2] += w0 * bf2f(x0.z); p0[3] += w0 * bf2f(x0.w);
    }
    size_t ob = (((size_t)node) << 7) + loff;
    ushort4 o0;
    o0.x = f2bf(p0[0] + p1[0]); o0.y = f2bf(p0[1] + p1[1]);
    o0.z = f2bf(p0[2] + p1[2]); o0.w = f2bf(p0[3] + p1[3]);
    *reinterpret_cast<ushort4*>(agg0 + ob) = o0;
}

// ---------------------------------------------------------------------------
// GEMM gates r|u: 128x128 tile, y-grid=2 over 256 cols, K=512, 512 threads,
// 8 waves (2x4), wave tile 64x32 (acc 4x2), double-buffered LDS (32KB).
// A parts: x,h from xh (stride 256), aggx/aggh (stride 128). B = W1b k-octet.
// Epilogue: col<128 -> rhb = bf16(sigmoid*h); col>=128 -> u = sigmoid (f32)
// ---------------------------------------------------------------------------
__global__ __launch_bounds__(512) void gemm_ru(
    const unsigned short* __restrict__ XH,
    const unsigned short* __restrict__ AGGX, const unsigned short* __restrict__ AGGH,
    const unsigned short* __restrict__ Wb, const float* __restrict__ bias,
    const float* __restrict__ hfull,
    unsigned short* __restrict__ rhb, float* __restrict__ u, int N) {
    __shared__ __align__(16) unsigned short Als[2][4 * 128 * 8];  // 8KB x2
    __shared__ __align__(16) unsigned short Bls[2][4 * 128 * 8];  // 8KB x2

    int tid = threadIdx.x;
    int row0 = blockIdx.x * 128;
    int n0c = blockIdx.y * 128;
    int lane = tid & 63;
    int w = tid >> 6;               // 8 waves
    int wrow = (w & 1) << 6;        // 0 / 64
    int wcol = (w >> 1) << 5;       // 0 / 32 / 64 / 96
    int quad = lane >> 4, l16 = lane & 15;

    f32x4 acc[4][2];
    const f32x4 z4 = {0.f, 0.f, 0.f, 0.f};
#pragma unroll
    for (int mt = 0; mt < 4; ++mt)
#pragma unroll
        for (int nt = 0; nt < 2; ++nt) acc[mt][nt] = z4;

    int mA = tid & 127, qA = tid >> 7;  // staging: one (q,m) pair per thread
    int growA = row0 + mA;
    if (growA >= N) growA = N - 1;
    int nB = tid & 127, qB = tid >> 7;

    auto stage = [&](int ks, int buf) {
        int p = ks >> 7;
        const unsigned short* ga =
            (p == 0) ? (XH + (size_t)growA * 256 + (ks & 127) + (qA << 3))
          : (p == 1) ? (XH + (size_t)growA * 256 + 128 + (ks & 127) + (qA << 3))
          : (p == 2) ? (AGGX + ((size_t)growA << 7) + (ks & 127) + (qA << 3))
                     : (AGGH + ((size_t)growA << 7) + (ks & 127) + (qA << 3));
        __builtin_amdgcn_global_load_lds(
            (const __attribute__((address_space(1))) void*)ga,
            (__attribute__((address_space(3))) void*)&Als[buf][((qA << 7) + mA) << 3], 16, 0, 0);
        int koG = (ks >> 3) + qB;
        const unsigned short* gb = Wb + ((size_t)(koG * 256 + n0c + nB) << 3);
        __builtin_amdgcn_global_load_lds(
            (const __attribute__((address_space(1))) void*)gb,
            (__attribute__((address_space(3))) void*)&Bls[buf][((qB << 7) + nB) << 3], 16, 0, 0);
    };

    stage(0, 0);
    __syncthreads();
    int buf = 0;
    for (int ks = 0; ks < 512; ks += 32, buf ^= 1) {
        if (ks + 32 < 512) stage(ks + 32, buf ^ 1);

        bf16x8s af[4], bfr[2];
#pragma unroll
        for (int mt = 0; mt < 4; ++mt)
            af[mt] = *reinterpret_cast<const bf16x8s*>(
                &Als[buf][((quad << 7) + wrow + (mt << 4) + l16) << 3]);
#pragma unroll
        for (int nt = 0; nt < 2; ++nt)
            bfr[nt] = *reinterpret_cast<const bf16x8s*>(
                &Bls[buf][((quad << 7) + wcol + (nt << 4) + l16) << 3]);
#pragma unroll
        for (int mt = 0; mt < 4; ++mt)
#pragma unroll
            for (int nt = 0; nt < 2; ++nt)
                acc[mt][nt] = __builtin_amdgcn_mfma_f32_16x16x32_bf16(
                    af[mt], bfr[nt], acc[mt][nt], 0, 0, 0);
        __syncthreads();
    }

#pragma unroll
    for (int mt = 0; mt < 4; ++mt) {
#pragma unroll
        for (int reg = 0; reg < 4; ++reg) {
            int row = row0 + wrow + (mt << 4) + (quad << 2) + reg;
            if (row >= N) continue;
#pragma unroll
            for (int nt = 0; nt < 2; ++nt) {
                int col = n0c + wcol + (nt << 4) + l16;
                float val = acc[mt][nt][reg] + bias[col];
                float sg = sigmoidf_(val);
                int c = col & 127;
                size_t o = ((size_t)row << 7) + c;
                if (col < 128)
                    rhb[o] = f2bf(sg * hfull[o]);   // rh = r*h (bf16)
                else
                    u[o] = sg;                       // u (f32)
            }
        }
    }
}

// ---------------------------------------------------------------------------
// GEMM gate c: 128x128 tile, K=512, 512 threads, 8 waves (2x4), acc 4x2.
// A parts: x (xh stride 256), rh (128), aggx (128), agg_rh (128). B = W2b.
// Epilogue: c = sigmoid; hn = u*h+(1-u)*c -> outf (+outf2); outb = bf16(hn)
// with row shift obsh (8 -> next xh cols 0:128, 7 -> plain 128-col table).
// ---------------------------------------------------------------------------
__global__ __launch_bounds__(512) void gemm_c(
    const unsigned short* __restrict__ XH, const unsigned short* __restrict__ RHB,
    const unsigned short* __restrict__ AGGX, const unsigned short* __restrict__ AGGR,
    const unsigned short* __restrict__ Wb, const float* __restrict__ bias,
    const float* __restrict__ hfull, const float* __restrict__ uin,
    unsigned short* __restrict__ outb, float* __restrict__ outf,
    float* __restrict__ outf2, int obsh, int N) {
    __shared__ __align__(16) unsigned short Als[2][4 * 128 * 8];  // 8KB x2
    __shared__ __align__(16) unsigned short Bls[2][4 * 128 * 8];  // 8KB x2

    int tid = threadIdx.x;
    int row0 = blockIdx.x * 128;
    int lane = tid & 63;
    int w = tid >> 6;
    int wrow = (w & 1) << 6;
    int wcol = (w >> 1) << 5;
    int quad = lane >> 4, l16 = lane & 15;

    f32x4 acc[4][2];
    const f32x4 z4 = {0.f, 0.f, 0.f, 0.f};
#pragma unroll
    for (int mt = 0; mt < 4; ++mt)
#pragma unroll
        for (int nt = 0; nt < 2; ++nt) acc[mt][nt] = z4;

    int mA = tid & 127, qA = tid >> 7;
    int growA = row0 + mA;
    if (growA >= N) growA = N - 1;
    int nB = tid & 127, qB = tid >> 7;

    auto stage = [&](int ks, int buf) {
        int p = ks >> 7;
        const unsigned short* ga =
            (p == 0) ? (XH + (size_t)growA * 256 + (ks & 127) + (qA << 3))
          : (p == 1) ? (RHB + ((size_t)growA << 7) + (ks & 127) + (qA << 3))
          : (p == 2) ? (AGGX + ((size_t)growA << 7) + (ks & 127) + (qA << 3))
                     : (AGGR + ((size_t)growA << 7) + (ks & 127) + (qA << 3));
        __builtin_amdgcn_global_load_lds(
            (const __attribute__((address_space(1))) void*)ga,
            (__attribute__((address_space(3))) void*)&Als[buf][((qA << 7) + mA) << 3], 16, 0, 0);
        int koG = (ks >> 3) + qB;
        const unsigned short* gb = Wb + ((size_t)(koG * 128 + nB) << 3);
        __builtin_amdgcn_global_load_lds(
            (const __attribute__((address_space(1))) void*)gb,
            (__attribute__((address_space(3))) void*)&Bls[buf][((qB << 7) + nB) << 3], 16, 0, 0);
    };

    stage(0, 0);
    __syncthreads();
    int buf = 0;
    for (int ks = 0; ks < 512; ks += 32, buf ^= 1) {
        if (ks + 32 < 512) stage(ks + 32, buf ^ 1);

        bf16x8s af[4], bfr[2];
#pragma unroll
        for (int mt = 0; mt < 4; ++mt)
            af[mt] = *reinterpret_cast<const bf16x8s*>(
                &Als[buf][((quad << 7) + wrow + (mt << 4) + l16) << 3]);
#pragma unroll
        for (int nt = 0; nt < 2; ++nt)
            bfr[nt] = *reinterpret_cast<const bf16x8s*>(
                &Bls[buf][((quad << 7) + wcol + (nt << 4) + l16) << 3]);
#pragma unroll
        for (int mt = 0; mt < 4; ++mt)
#pragma unroll
            for (int nt = 0; nt < 2; ++nt)
                acc[mt][nt] = __builtin_amdgcn_mfma_f32_16x16x32_bf16(
                    af[mt], bfr[nt], acc[mt][nt], 0, 0, 0);
        __syncthreads();
    }

#pragma unroll
    for (int mt = 0; mt < 4; ++mt) {
#pragma unroll
        for (int reg = 0; reg < 4; ++reg) {
            int row = row0 + wrow + (mt << 4) + (quad << 2) + reg;
            if (row >= N) continue;
#pragma unroll
            for (int nt = 0; nt < 2; ++nt) {
                int col = wcol + (nt << 4) + l16;
                float val = acc[mt][nt][reg] + bias[col];
                float cv = sigmoidf_(val);
                size_t o = ((size_t)row << 7) + col;
                float uu = uin[o];
                float hh = hfull[o];
                float hn = uu * hh + (1.0f - uu) * cv;
                outf[o] = hn;
                if (outf2) outf2[o] = hn;
                outb[((size_t)row << obsh) + col] = f2bf(hn);  // next layer's x
            }
        }
    }
}

// ---------------------------------------------------------------------------
extern "C" void kernel_launch(void* const* d_in, const int* in_sizes, int n_in,
                              void* d_out, int out_size, void* d_ws, size_t ws_size,
                              hipStream_t stream) {
    const float* x      = (const float*)d_in[0];
    const float* hidden = (const float*)d_in[1];
    const int*   src    = (const int*)d_in[2];
    const int*   dst    = (const int*)d_in[3];
    const float* ew     = (const float*)d_in[4];
    const float* Wself  = (const float*)d_in[5];
    const float* Wneigh = (const float*)d_in[6];
    const float* bias   = (const float*)d_in[7];
    float* out = (float*)d_out;

    int N = in_sizes[0] / F;  // 50000
    int E = in_sizes[2];      // 800000
    size_t NF = (size_t)N * F;

    char* p = (char*)d_ws;
    auto alloc = [&](size_t bytes) { char* r = p; p += (bytes + 255) & ~255ull; return r; };
    unsigned short* xh0    = (unsigned short*)alloc(2 * NF * 2);  // [N][256] x|h layer0
    unsigned short* xh1    = (unsigned short*)alloc(2 * NF * 2);  // [N][256] x|h layer1
    unsigned short* agg_xb = (unsigned short*)alloc(NF * 2);
    unsigned short* agg_hb = (unsigned short*)alloc(NF * 2);
    unsigned short* agg_rb = (unsigned short*)alloc(NF * 2);
    unsigned short* rhb    = (unsigned short*)alloc(NF * 2);
    float*          u      = (float*)alloc(NF * 4);
    unsigned short* W1b    = (unsigned short*)alloc(2 * 64 * 256 * 8 * 2);
    unsigned short* W2b    = (unsigned short*)alloc(2 * 64 * 128 * 8 * 2);
    int2*           es     = (int2*)alloc((size_t)E * 8);
    int*            cnt    = (int*)alloc((size_t)N * 4);
    int*            offs   = (int*)alloc(((size_t)N + 1) * 4);
    int*            cursor = (int*)alloc((size_t)N * 4);
    int*            bsum   = (int*)alloc(1024 * 4);

    hipMemsetAsync(cnt, 0, (size_t)N * sizeof(int), stream);

    int n4 = (int)(NF / 4);
    int cvtBlocks = (3 * n4 + 255) / 256;
    int histBlocks = (E / 2 + 255) / 256;
    prologue<<<dim3(cvtBlocks + 1536 + histBlocks), dim3(256), 0, stream>>>(
        x, hidden, Wself, Wneigh, dst, xh0, xh1, W1b, W2b, cnt, n4, NF, E, cvtBlocks);

    int nb = (N + 1023) / 1024;  // 49
    scan_blk<<<dim3(nb), dim3(1024), 0, stream>>>(cnt, offs, bsum, N);
    scan_tops<<<dim3(1), dim3(1024), 0, stream>>>(bsum, nb, offs + N);
    scan_add<<<dim3(nb), dim3(1024), 0, stream>>>(bsum, offs, cursor, N);
    int e2Blocks = (E / 2 + 255) / 256;
    scatter_edges<<<dim3(e2Blocks), dim3(256), 0, stream>>>(src, dst, ew, cursor, es, E);

    float* out_x  = out;
    float* out_h1 = out + NF;
    float* out_h2 = out + 2 * NF;

    int aggBlocks = (N + 7) / 8;
    int mBlocks = (N + 127) / 128;  // 391
    for (int l = 0; l < NLAYERS; ++l) {
        unsigned short* xhL = (l == 0) ? xh0 : xh1;
        const float* hL = hidden + (size_t)l * NF;
        const float* biasL = bias + (size_t)l * 384;

        agg_csr2_i<<<dim3(aggBlocks), dim3(256), 0, stream>>>(xhL, es, offs,
                                                              agg_xb, agg_hb, N);

        gemm_ru<<<dim3(mBlocks, 2), dim3(512), 0, stream>>>(
            xhL, agg_xb, agg_hb,
            W1b + (size_t)l * 64 * 256 * 8, biasL, hL,
            rhb, u, N);

        agg_csr1_b<<<dim3(aggBlocks), dim3(256), 0, stream>>>(rhb, es, offs, agg_rb, N);

        float* o1 = (l == 0) ? out_h1 : out_h2;
        float* o2 = (l == NLAYERS - 1) ? out_x : nullptr;
        // l==0: outb -> xh1 cols 0:128 (stride 256, obsh=8) = next layer's x.
        // l==1: outb dead; reuse agg_rb (each block writes only its own rows,
        //       after its last staged read of them) with obsh=7.
        unsigned short* obN = (l == 0) ? xh1 : agg_rb;
        int obsh = (l == 0) ? 8 : 7;
        gemm_c<<<dim3(mBlocks), dim3(512), 0, stream>>>(
            xhL, rhb, agg_xb, agg_rb,
            W2b + (size_t)l * 64 * 128 * 8, biasL + 256, hL, u,
            obN, o1, o2, obsh, N);
    }
}

// Round 11
// 570.205 us; speedup vs baseline: 1.0426x; 1.0346x over previous
//
#include <hip/hip_runtime.h>
#include <math.h>

#define F 128
#define NLAYERS 2

typedef __attribute__((ext_vector_type(8))) short bf16x8s;
typedef __attribute__((ext_vector_type(8))) unsigned short u16x8;
typedef __attribute__((ext_vector_type(4))) float f32x4;

__device__ __forceinline__ float sigmoidf_(float x) { return 1.0f / (1.0f + expf(-x)); }

__device__ __forceinline__ unsigned short f2bf(float f) {
    unsigned int u = __float_as_uint(f);
    u += 0x7fffu + ((u >> 16) & 1u);  // RNE
    return (unsigned short)(u >> 16);
}
__device__ __forceinline__ float bf2f(unsigned short s) {
    return __uint_as_float(((unsigned int)s) << 16);
}

// ---------------------------------------------------------------------------
// Fused prologue: one dispatch covering three independent jobs by block range.
// ---------------------------------------------------------------------------
__global__ void prologue(const float* __restrict__ x, const float* __restrict__ hidden,
                         const float* __restrict__ Ws, const float* __restrict__ Wn,
                         const int* __restrict__ dst,
                         unsigned short* __restrict__ xh0, unsigned short* __restrict__ xh1,
                         unsigned short* __restrict__ W1b, unsigned short* __restrict__ W2b,
                         int* __restrict__ cnt, int n4, size_t NF, int E, int cvtBlocks) {
    int b = blockIdx.x;
    int tid = threadIdx.x;
    if (b < cvtBlocks) {
        int t = b * 256 + tid;
        const float* in;
        unsigned short* out;
        int tt;
        if (t < n4) { in = x; out = xh0; tt = t; }
        else if (t < 2 * n4) { in = hidden; out = xh0 + 128; tt = t - n4; }
        else if (t < 3 * n4) { in = hidden + NF; out = xh1 + 128; tt = t - 2 * n4; }
        else return;
        float4 v = reinterpret_cast<const float4*>(in)[tt];
        ushort4 o;
        o.x = f2bf(v.x); o.y = f2bf(v.y); o.z = f2bf(v.z); o.w = f2bf(v.w);
        *reinterpret_cast<ushort4*>(out + (((size_t)(tt >> 5)) << 8) + ((tt & 31) << 2)) = o;
    } else if (b < cvtBlocks + 1536) {
        int t = (b - cvtBlocks) * 256 + tid;
        const int n1 = 2 * 64 * 256 * 8;  // 262144
        if (t < n1) {
            int j = t & 7, n = (t >> 3) & 255, ko = (t >> 11) & 63, l = t >> 17;
            int k = ko * 8 + j;
            int p = k >> 7, r = k & 127, g = n >> 7, c = n & 127;
            const float* W = (p < 2) ? Ws : Wn;
            W1b[t] = f2bf(W[(((l * 3 + g) * 256) + ((p & 1) * 128 + r)) * 128 + c]);
        } else {
            int t2 = t - n1;
            if (t2 >= 2 * 64 * 128 * 8) return;
            int j = t2 & 7, n = (t2 >> 3) & 127, ko = (t2 >> 10) & 63, l = t2 >> 16;
            int k = ko * 8 + j;
            int p = k >> 7, r = k & 127;
            const float* W = (p < 2) ? Ws : Wn;
            W2b[t2] = f2bf(W[(((l * 3 + 2) * 256) + ((p & 1) * 128 + r)) * 128 + n]);
        }
    } else {
        int t = (b - cvtBlocks - 1536) * 256 + tid;
        int e = t << 1;
        if (e + 1 < E) {
            int2 d = *reinterpret_cast<const int2*>(dst + e);
            atomicAdd(&cnt[d.x], 1);
            atomicAdd(&cnt[d.y], 1);
        } else if (e < E) {
            atomicAdd(&cnt[dst[e]], 1);
        }
    }
}

// ---------------------------------------------------------------------------
// Parallel exclusive scan over N node counts (3 kernels).
// ---------------------------------------------------------------------------
__global__ __launch_bounds__(1024) void scan_blk(const int* __restrict__ cnt,
                                                 int* __restrict__ offs,
                                                 int* __restrict__ bsum, int n) {
    __shared__ int wsum[16];
    int tid = threadIdx.x, lane = tid & 63, wid = tid >> 6;
    int i = blockIdx.x * 1024 + tid;
    int v = (i < n) ? cnt[i] : 0;
    int incl = v;
#pragma unroll
    for (int off = 1; off < 64; off <<= 1) {
        int t = __shfl_up(incl, off, 64);
        if (lane >= off) incl += t;
    }
    if (lane == 63) wsum[wid] = incl;
    __syncthreads();
    if (wid == 0) {
        int s = (lane < 16) ? wsum[lane] : 0;
#pragma unroll
        for (int off = 1; off < 16; off <<= 1) {
            int t = __shfl_up(s, off, 64);
            if (lane >= off) s += t;
        }
        if (lane < 16) wsum[lane] = s;
    }
    __syncthreads();
    int wbase = (wid > 0) ? wsum[wid - 1] : 0;
    if (i < n) offs[i] = wbase + incl - v;
    if (tid == 1023) bsum[blockIdx.x] = wbase + incl;
}

__global__ __launch_bounds__(1024) void scan_tops(int* __restrict__ bsum, int nb,
                                                  int* __restrict__ total_out) {
    __shared__ int wsum[16];
    int tid = threadIdx.x, lane = tid & 63, wid = tid >> 6;
    int v = (tid < nb) ? bsum[tid] : 0;
    int incl = v;
#pragma unroll
    for (int off = 1; off < 64; off <<= 1) {
        int t = __shfl_up(incl, off, 64);
        if (lane >= off) incl += t;
    }
    if (lane == 63) wsum[wid] = incl;
    __syncthreads();
    if (wid == 0) {
        int s = (lane < 16) ? wsum[lane] : 0;
#pragma unroll
        for (int off = 1; off < 16; off <<= 1) {
            int t = __shfl_up(s, off, 64);
            if (lane >= off) s += t;
        }
        if (lane < 16) wsum[lane] = s;
    }
    __syncthreads();
    int wbase = (wid > 0) ? wsum[wid - 1] : 0;
    if (tid < nb) bsum[tid] = wbase + incl - v;
    if (tid == 1023) *total_out = wbase + incl;
}

__global__ __launch_bounds__(1024) void scan_add(const int* __restrict__ bsum,
                                                 int* __restrict__ offs,
                                                 int* __restrict__ cursor, int n) {
    int i = blockIdx.x * 1024 + threadIdx.x;
    if (i >= n) return;
    int o = offs[i] + bsum[blockIdx.x];
    offs[i] = o;
    cursor[i] = o;
}

// Scatter edges into CSR order (unroll-2).
__global__ void scatter_edges(const int* __restrict__ src, const int* __restrict__ dst,
                              const float* __restrict__ ew, int* __restrict__ cursor,
                              int2* __restrict__ es, int E) {
    int t = blockIdx.x * blockDim.x + threadIdx.x;
    int e = t << 1;
    if (e + 1 < E) {
        int2 s = *reinterpret_cast<const int2*>(src + e);
        int2 d = *reinterpret_cast<const int2*>(dst + e);
        float2 w = *reinterpret_cast<const float2*>(ew + e);
        int p0 = atomicAdd(&cursor[d.x], 1);
        int p1 = atomicAdd(&cursor[d.y], 1);
        es[p0] = make_int2(s.x, __float_as_int(w.x));
        es[p1] = make_int2(s.y, __float_as_int(w.y));
    } else if (e < E) {
        int s = src[e];
        int p = atomicAdd(&cursor[dst[e]], 1);
        es[p] = make_int2(s, __float_as_int(ew[e]));
    }
}

// ---------------------------------------------------------------------------
// CSR aggregation over interleaved xh[N][256] bf16.
// ---------------------------------------------------------------------------
__global__ __launch_bounds__(256) void agg_csr2_i(
    const unsigned short* __restrict__ XH,
    const int2* __restrict__ es, const int* __restrict__ offs,
    unsigned short* __restrict__ agg0, unsigned short* __restrict__ agg1, int N) {
    int node = blockIdx.x * 8 + (threadIdx.x >> 5);
    if (node >= N) return;
    int lane = threadIdx.x & 31;
    int beg = offs[node], end = offs[node + 1];
    float a0[8] = {0, 0, 0, 0, 0, 0, 0, 0};
    float a1[8] = {0, 0, 0, 0, 0, 0, 0, 0};
    int loff = lane << 3;
    int i = beg;
    for (; i + 3 < end; i += 4) {
        int2 e0 = es[i], e1 = es[i + 1], e2 = es[i + 2], e3 = es[i + 3];
        u16x8 v0 = *reinterpret_cast<const u16x8*>(XH + (((size_t)e0.x) << 8) + loff);
        u16x8 v1 = *reinterpret_cast<const u16x8*>(XH + (((size_t)e1.x) << 8) + loff);
        u16x8 v2 = *reinterpret_cast<const u16x8*>(XH + (((size_t)e2.x) << 8) + loff);
        u16x8 v3 = *reinterpret_cast<const u16x8*>(XH + (((size_t)e3.x) << 8) + loff);
        float w0 = __int_as_float(e0.y), w1 = __int_as_float(e1.y);
        float w2 = __int_as_float(e2.y), w3 = __int_as_float(e3.y);
#pragma unroll
        for (int j = 0; j < 8; ++j) {
            a0[j] += w0 * bf2f(v0[j]);
            a1[j] += w1 * bf2f(v1[j]);
            a0[j] += w2 * bf2f(v2[j]);
            a1[j] += w3 * bf2f(v3[j]);
        }
    }
    for (; i < end; ++i) {
        int2 e0 = es[i];
        float w0 = __int_as_float(e0.y);
        u16x8 v0 = *reinterpret_cast<const u16x8*>(XH + (((size_t)e0.x) << 8) + loff);
#pragma unroll
        for (int j = 0; j < 8; ++j) a0[j] += w0 * bf2f(v0[j]);
    }
    u16x8 o;
#pragma unroll
    for (int j = 0; j < 8; ++j) o[j] = f2bf(a0[j] + a1[j]);
    unsigned short* op = (lane < 16)
        ? (agg0 + (((size_t)node) << 7) + (lane << 3))
        : (agg1 + (((size_t)node) << 7) + ((lane & 15) << 3));
    *reinterpret_cast<u16x8*>(op) = o;
}

// Single-table CSR aggregation (rh, [N][128] bf16).
__global__ __launch_bounds__(256) void agg_csr1_b(
    const unsigned short* __restrict__ V0,
    const int2* __restrict__ es, const int* __restrict__ offs,
    unsigned short* __restrict__ agg0, int N) {
    int node = blockIdx.x * 8 + (threadIdx.x >> 5);
    if (node >= N) return;
    int lane = threadIdx.x & 31;
    int beg = offs[node], end = offs[node + 1];
    float p0[4] = {0, 0, 0, 0}, p1[4] = {0, 0, 0, 0};
    int loff = lane << 2;
    int i = beg;
    for (; i + 3 < end; i += 4) {
        int2 e0 = es[i], e1 = es[i + 1], e2 = es[i + 2], e3 = es[i + 3];
        ushort4 x0 = *reinterpret_cast<const ushort4*>(V0 + (((size_t)e0.x) << 7) + loff);
        ushort4 x1 = *reinterpret_cast<const ushort4*>(V0 + (((size_t)e1.x) << 7) + loff);
        ushort4 x2 = *reinterpret_cast<const ushort4*>(V0 + (((size_t)e2.x) << 7) + loff);
        ushort4 x3 = *reinterpret_cast<const ushort4*>(V0 + (((size_t)e3.x) << 7) + loff);
        float w0 = __int_as_float(e0.y), w1 = __int_as_float(e1.y);
        float w2 = __int_as_float(e2.y), w3 = __int_as_float(e3.y);
        p0[0] += w0 * bf2f(x0.x); p0[1] += w0 * bf2f(x0.y);
        p0[2] += w0 * bf2f(x0.z); p0[3] += w0 * bf2f(x0.w);
        p1[0] += w1 * bf2f(x1.x); p1[1] += w1 * bf2f(x1.y);
        p1[2] += w1 * bf2f(x1.z); p1[3] += w1 * bf2f(x1.w);
        p0[0] += w2 * bf2f(x2.x); p0[1] += w2 * bf2f(x2.y);
        p0[2] += w2 * bf2f(x2.z); p0[3] += w2 * bf2f(x2.w);
        p1[0] += w3 * bf2f(x3.x); p1[1] += w3 * bf2f(x3.y);
        p1[2] += w3 * bf2f(x3.z); p1[3] += w3 * bf2f(x3.w);
    }
    for (; i < end; ++i) {
        int2 e0 = es[i];
        float w0 = __int_as_float(e0.y);
        ushort4 x0 = *reinterpret_cast<const ushort4*>(V0 + (((size_t)e0.x) << 7) + loff);
        p0[0] += w0 * bf2f(x0.x); p0[1] += w0 * bf2f(x0.y);
        p0[2] += w0 * bf2f(x0.z); p0[3] += w0 * bf2f(x0.w);
    }
    size_t ob = (((size_t)node) << 7) + loff;
    ushort4 o0;
    o0.x = f2bf(p0[0] + p1[0]); o0.y = f2bf(p0[1] + p1[1]);
    o0.z = f2bf(p0[2] + p1[2]); o0.w = f2bf(p0[3] + p1[3]);
    *reinterpret_cast<ushort4*>(agg0 + ob) = o0;
}

// ---------------------------------------------------------------------------
// GEMM gates r|u: 128x128 tile, y-grid=2, K=512, 512 threads, 8 waves (2x4),
// acc 4x2, double-buffered LDS, COUNTED-vmcnt pipeline:
//   stage(t+1) -> vmcnt(2) -> barrier -> ds_read+MFMA -> lgkmcnt(0) -> barrier
// Tile t+1's 2 loads/thread stay in flight across the whole compute phase.
// ---------------------------------------------------------------------------
__global__ __launch_bounds__(512) void gemm_ru(
    const unsigned short* __restrict__ XH,
    const unsigned short* __restrict__ AGGX, const unsigned short* __restrict__ AGGH,
    const unsigned short* __restrict__ Wb, const float* __restrict__ bias,
    const float* __restrict__ hfull,
    unsigned short* __restrict__ rhb, float* __restrict__ u, int N) {
    __shared__ __align__(16) unsigned short Als[2][4 * 128 * 8];  // 8KB x2
    __shared__ __align__(16) unsigned short Bls[2][4 * 128 * 8];  // 8KB x2

    int tid = threadIdx.x;
    int row0 = blockIdx.x * 128;
    int n0c = blockIdx.y * 128;
    int lane = tid & 63;
    int w = tid >> 6;               // 8 waves
    int wrow = (w & 1) << 6;        // 0 / 64
    int wcol = (w >> 1) << 5;       // 0 / 32 / 64 / 96
    int quad = lane >> 4, l16 = lane & 15;

    f32x4 acc[4][2];
    const f32x4 z4 = {0.f, 0.f, 0.f, 0.f};
#pragma unroll
    for (int mt = 0; mt < 4; ++mt)
#pragma unroll
        for (int nt = 0; nt < 2; ++nt) acc[mt][nt] = z4;

    int mA = tid & 127, qA = tid >> 7;  // staging: one (q,m) pair per thread
    int growA = row0 + mA;
    if (growA >= N) growA = N - 1;
    int nB = tid & 127, qB = tid >> 7;

    auto stage = [&](int ks, int buf) {
        int p = ks >> 7;
        const unsigned short* ga =
            (p == 0) ? (XH + (size_t)growA * 256 + (ks & 127) + (qA << 3))
          : (p == 1) ? (XH + (size_t)growA * 256 + 128 + (ks & 127) + (qA << 3))
          : (p == 2) ? (AGGX + ((size_t)growA << 7) + (ks & 127) + (qA << 3))
                     : (AGGH + ((size_t)growA << 7) + (ks & 127) + (qA << 3));
        __builtin_amdgcn_global_load_lds(
            (const __attribute__((address_space(1))) void*)ga,
            (__attribute__((address_space(3))) void*)&Als[buf][((qA << 7) + mA) << 3], 16, 0, 0);
        int koG = (ks >> 3) + qB;
        const unsigned short* gb = Wb + ((size_t)(koG * 256 + n0c + nB) << 3);
        __builtin_amdgcn_global_load_lds(
            (const __attribute__((address_space(1))) void*)gb,
            (__attribute__((address_space(3))) void*)&Bls[buf][((qB << 7) + nB) << 3], 16, 0, 0);
    };

    stage(0, 0);
    int buf = 0;
    for (int ks = 0; ks < 512; ks += 32, buf ^= 1) {
        if (ks + 32 < 512) {
            stage(ks + 32, buf ^ 1);
            asm volatile("s_waitcnt vmcnt(2)" ::: "memory");  // tile t done; t+1 in flight
        } else {
            asm volatile("s_waitcnt vmcnt(0)" ::: "memory");
        }
        __builtin_amdgcn_s_barrier();       // #1: tile t fully in LDS (all waves)
        __builtin_amdgcn_sched_barrier(0);  // keep ds_reads below the barrier

        bf16x8s af[4], bfr[2];
#pragma unroll
        for (int mt = 0; mt < 4; ++mt)
            af[mt] = *reinterpret_cast<const bf16x8s*>(
                &Als[buf][((quad << 7) + wrow + (mt << 4) + l16) << 3]);
#pragma unroll
        for (int nt = 0; nt < 2; ++nt)
            bfr[nt] = *reinterpret_cast<const bf16x8s*>(
                &Bls[buf][((quad << 7) + wcol + (nt << 4) + l16) << 3]);
#pragma unroll
        for (int mt = 0; mt < 4; ++mt)
#pragma unroll
            for (int nt = 0; nt < 2; ++nt)
                acc[mt][nt] = __builtin_amdgcn_mfma_f32_16x16x32_bf16(
                    af[mt], bfr[nt], acc[mt][nt], 0, 0, 0);

        asm volatile("s_waitcnt lgkmcnt(0)" ::: "memory");  // ds_reads complete
        __builtin_amdgcn_sched_barrier(0);
        __builtin_amdgcn_s_barrier();       // #2: buf free for next-iter staging
    }

#pragma unroll
    for (int mt = 0; mt < 4; ++mt) {
#pragma unroll
        for (int reg = 0; reg < 4; ++reg) {
            int row = row0 + wrow + (mt << 4) + (quad << 2) + reg;
            if (row >= N) continue;
#pragma unroll
            for (int nt = 0; nt < 2; ++nt) {
                int col = n0c + wcol + (nt << 4) + l16;
                float val = acc[mt][nt][reg] + bias[col];
                float sg = sigmoidf_(val);
                int c = col & 127;
                size_t o = ((size_t)row << 7) + c;
                if (col < 128)
                    rhb[o] = f2bf(sg * hfull[o]);   // rh = r*h (bf16)
                else
                    u[o] = sg;                       // u (f32)
            }
        }
    }
}

// ---------------------------------------------------------------------------
// GEMM gate c: 128x128 tile, K=512, same counted-vmcnt pipeline.
// ---------------------------------------------------------------------------
__global__ __launch_bounds__(512) void gemm_c(
    const unsigned short* __restrict__ XH, const unsigned short* __restrict__ RHB,
    const unsigned short* __restrict__ AGGX, const unsigned short* __restrict__ AGGR,
    const unsigned short* __restrict__ Wb, const float* __restrict__ bias,
    const float* __restrict__ hfull, const float* __restrict__ uin,
    unsigned short* __restrict__ outb, float* __restrict__ outf,
    float* __restrict__ outf2, int obsh, int N) {
    __shared__ __align__(16) unsigned short Als[2][4 * 128 * 8];  // 8KB x2
    __shared__ __align__(16) unsigned short Bls[2][4 * 128 * 8];  // 8KB x2

    int tid = threadIdx.x;
    int row0 = blockIdx.x * 128;
    int lane = tid & 63;
    int w = tid >> 6;
    int wrow = (w & 1) << 6;
    int wcol = (w >> 1) << 5;
    int quad = lane >> 4, l16 = lane & 15;

    f32x4 acc[4][2];
    const f32x4 z4 = {0.f, 0.f, 0.f, 0.f};
#pragma unroll
    for (int mt = 0; mt < 4; ++mt)
#pragma unroll
        for (int nt = 0; nt < 2; ++nt) acc[mt][nt] = z4;

    int mA = tid & 127, qA = tid >> 7;
    int growA = row0 + mA;
    if (growA >= N) growA = N - 1;
    int nB = tid & 127, qB = tid >> 7;

    auto stage = [&](int ks, int buf) {
        int p = ks >> 7;
        const unsigned short* ga =
            (p == 0) ? (XH + (size_t)growA * 256 + (ks & 127) + (qA << 3))
          : (p == 1) ? (RHB + ((size_t)growA << 7) + (ks & 127) + (qA << 3))
          : (p == 2) ? (AGGX + ((size_t)growA << 7) + (ks & 127) + (qA << 3))
                     : (AGGR + ((size_t)growA << 7) + (ks & 127) + (qA << 3));
        __builtin_amdgcn_global_load_lds(
            (const __attribute__((address_space(1))) void*)ga,
            (__attribute__((address_space(3))) void*)&Als[buf][((qA << 7) + mA) << 3], 16, 0, 0);
        int koG = (ks >> 3) + qB;
        const unsigned short* gb = Wb + ((size_t)(koG * 128 + nB) << 3);
        __builtin_amdgcn_global_load_lds(
            (const __attribute__((address_space(1))) void*)gb,
            (__attribute__((address_space(3))) void*)&Bls[buf][((qB << 7) + nB) << 3], 16, 0, 0);
    };

    stage(0, 0);
    int buf = 0;
    for (int ks = 0; ks < 512; ks += 32, buf ^= 1) {
        if (ks + 32 < 512) {
            stage(ks + 32, buf ^ 1);
            asm volatile("s_waitcnt vmcnt(2)" ::: "memory");
        } else {
            asm volatile("s_waitcnt vmcnt(0)" ::: "memory");
        }
        __builtin_amdgcn_s_barrier();
        __builtin_amdgcn_sched_barrier(0);

        bf16x8s af[4], bfr[2];
#pragma unroll
        for (int mt = 0; mt < 4; ++mt)
            af[mt] = *reinterpret_cast<const bf16x8s*>(
                &Als[buf][((quad << 7) + wrow + (mt << 4) + l16) << 3]);
#pragma unroll
        for (int nt = 0; nt < 2; ++nt)
            bfr[nt] = *reinterpret_cast<const bf16x8s*>(
                &Bls[buf][((quad << 7) + wcol + (nt << 4) + l16) << 3]);
#pragma unroll
        for (int mt = 0; mt < 4; ++mt)
#pragma unroll
            for (int nt = 0; nt < 2; ++nt)
                acc[mt][nt] = __builtin_amdgcn_mfma_f32_16x16x32_bf16(
                    af[mt], bfr[nt], acc[mt][nt], 0, 0, 0);

        asm volatile("s_waitcnt lgkmcnt(0)" ::: "memory");
        __builtin_amdgcn_sched_barrier(0);
        __builtin_amdgcn_s_barrier();
    }

#pragma unroll
    for (int mt = 0; mt < 4; ++mt) {
#pragma unroll
        for (int reg = 0; reg < 4; ++reg) {
            int row = row0 + wrow + (mt << 4) + (quad << 2) + reg;
            if (row >= N) continue;
#pragma unroll
            for (int nt = 0; nt < 2; ++nt) {
                int col = wcol + (nt << 4) + l16;
                float val = acc[mt][nt][reg] + bias[col];
                float cv = sigmoidf_(val);
                size_t o = ((size_t)row << 7) + col;
                float uu = uin[o];
                float hh = hfull[o];
                float hn = uu * hh + (1.0f - uu) * cv;
                outf[o] = hn;
                if (outf2) outf2[o] = hn;
                outb[((size_t)row << obsh) + col] = f2bf(hn);  // next layer's x
            }
        }
    }
}

// ---------------------------------------------------------------------------
extern "C" void kernel_launch(void* const* d_in, const int* in_sizes, int n_in,
                              void* d_out, int out_size, void* d_ws, size_t ws_size,
                              hipStream_t stream) {
    const float* x      = (const float*)d_in[0];
    const float* hidden = (const float*)d_in[1];
    const int*   src    = (const int*)d_in[2];
    const int*   dst    = (const int*)d_in[3];
    const float* ew     = (const float*)d_in[4];
    const float* Wself  = (const float*)d_in[5];
    const float* Wneigh = (const float*)d_in[6];
    const float* bias   = (const float*)d_in[7];
    float* out = (float*)d_out;

    int N = in_sizes[0] / F;  // 50000
    int E = in_sizes[2];      // 800000
    size_t NF = (size_t)N * F;

    char* p = (char*)d_ws;
    auto alloc = [&](size_t bytes) { char* r = p; p += (bytes + 255) & ~255ull; return r; };
    unsigned short* xh0    = (unsigned short*)alloc(2 * NF * 2);  // [N][256] x|h layer0
    unsigned short* xh1    = (unsigned short*)alloc(2 * NF * 2);  // [N][256] x|h layer1
    unsigned short* agg_xb = (unsigned short*)alloc(NF * 2);
    unsigned short* agg_hb = (unsigned short*)alloc(NF * 2);
    unsigned short* agg_rb = (unsigned short*)alloc(NF * 2);
    unsigned short* rhb    = (unsigned short*)alloc(NF * 2);
    float*          u      = (float*)alloc(NF * 4);
    unsigned short* W1b    = (unsigned short*)alloc(2 * 64 * 256 * 8 * 2);
    unsigned short* W2b    = (unsigned short*)alloc(2 * 64 * 128 * 8 * 2);
    int2*           es     = (int2*)alloc((size_t)E * 8);
    int*            cnt    = (int*)alloc((size_t)N * 4);
    int*            offs   = (int*)alloc(((size_t)N + 1) * 4);
    int*            cursor = (int*)alloc((size_t)N * 4);
    int*            bsum   = (int*)alloc(1024 * 4);

    hipMemsetAsync(cnt, 0, (size_t)N * sizeof(int), stream);

    int n4 = (int)(NF / 4);
    int cvtBlocks = (3 * n4 + 255) / 256;
    int histBlocks = (E / 2 + 255) / 256;
    prologue<<<dim3(cvtBlocks + 1536 + histBlocks), dim3(256), 0, stream>>>(
        x, hidden, Wself, Wneigh, dst, xh0, xh1, W1b, W2b, cnt, n4, NF, E, cvtBlocks);

    int nb = (N + 1023) / 1024;  // 49
    scan_blk<<<dim3(nb), dim3(1024), 0, stream>>>(cnt, offs, bsum, N);
    scan_tops<<<dim3(1), dim3(1024), 0, stream>>>(bsum, nb, offs + N);
    scan_add<<<dim3(nb), dim3(1024), 0, stream>>>(bsum, offs, cursor, N);
    int e2Blocks = (E / 2 + 255) / 256;
    scatter_edges<<<dim3(e2Blocks), dim3(256), 0, stream>>>(src, dst, ew, cursor, es, E);

    float* out_x  = out;
    float* out_h1 = out + NF;
    float* out_h2 = out + 2 * NF;

    int aggBlocks = (N + 7) / 8;
    int mBlocks = (N + 127) / 128;  // 391
    for (int l = 0; l < NLAYERS; ++l) {
        unsigned short* xhL = (l == 0) ? xh0 : xh1;
        const float* hL = hidden + (size_t)l * NF;
        const float* biasL = bias + (size_t)l * 384;

        agg_csr2_i<<<dim3(aggBlocks), dim3(256), 0, stream>>>(xhL, es, offs,
                                                              agg_xb, agg_hb, N);

        gemm_ru<<<dim3(mBlocks, 2), dim3(512), 0, stream>>>(
            xhL, agg_xb, agg_hb,
            W1b + (size_t)l * 64 * 256 * 8, biasL, hL,
            rhb, u, N);

        agg_csr1_b<<<dim3(aggBlocks), dim3(256), 0, stream>>>(rhb, es, offs, agg_rb, N);

        float* o1 = (l == 0) ? out_h1 : out_h2;
        float* o2 = (l == NLAYERS - 1) ? out_x : nullptr;
        // l==0: outb -> xh1 cols 0:128 (stride 256, obsh=8) = next layer's x.
        // l==1: outb dead; reuse agg_rb (each block writes only its own rows,
        //       after its last staged read of them) with obsh=7.
        unsigned short* obN = (l == 0) ? xh1 : agg_rb;
        int obsh = (l == 0) ? 8 : 7;
        gemm_c<<<dim3(mBlocks), dim3(512), 0, stream>>>(
            xhL, rhb, agg_xb, agg_rb,
            W2b + (size_t)l * 64 * 128 * 8, biasL + 256, hL, u,
            obN, o1, o2, obsh, N);
    }
}